// Round 4
// baseline (649.948 us; speedup 1.0000x reference)
//
#include <hip/hip_runtime.h>
#include <hip/hip_bf16.h>

#define N_NODES 100000
#define N_EDGES 1600000
#define D 64
#define NEG_SLOPE 0.2f
#define NB ((N_NODES + 255) / 256)   // 391 scan blocks

// ---------------------------------------------------------------------------
// Kernel 1: histogram of edges per destination node (int4-vectorized reads).
// ---------------------------------------------------------------------------
__global__ __launch_bounds__(256) void hist_kernel(
    const int4* __restrict__ dst4, int* __restrict__ cnt)
{
    int i = blockIdx.x * 256 + threadIdx.x;
    if (i < N_EDGES / 4) {                       // 1.6M % 4 == 0
        int4 d = dst4[i];
        atomicAdd(&cnt[d.x], 1);
        atomicAdd(&cnt[d.y], 1);
        atomicAdd(&cnt[d.z], 1);
        atomicAdd(&cnt[d.w], 1);
    }
}

// ---------------------------------------------------------------------------
// Scan phase A: per-block (256-wide) sums of cnt.
// ---------------------------------------------------------------------------
__global__ __launch_bounds__(256) void block_sum_kernel(
    const int* __restrict__ cnt, int* __restrict__ bsum)
{
    int i = blockIdx.x * 256 + threadIdx.x;
    int v = (i < N_NODES) ? cnt[i] : 0;
    #pragma unroll
    for (int o = 32; o > 0; o >>= 1) v += __shfl_down(v, o);
    __shared__ int ws[4];
    if ((threadIdx.x & 63) == 0) ws[threadIdx.x >> 6] = v;
    __syncthreads();
    if (threadIdx.x == 0) bsum[blockIdx.x] = ws[0] + ws[1] + ws[2] + ws[3];
}

// ---------------------------------------------------------------------------
// Scan phase B: exclusive scan of the 391 block sums (single small block).
// ---------------------------------------------------------------------------
__global__ __launch_bounds__(512) void scan_bsum_kernel(
    const int* __restrict__ bsum, int* __restrict__ boff)
{
    __shared__ int sh[512];
    int t = threadIdx.x;
    int v = (t < NB) ? bsum[t] : 0;
    sh[t] = v;
    __syncthreads();
    for (int d = 1; d < 512; d <<= 1) {
        int u = (t >= d) ? sh[t - d] : 0;
        __syncthreads();
        sh[t] += u;
        __syncthreads();
    }
    if (t < NB) boff[t] = sh[t] - v;          // exclusive prefix
}

// ---------------------------------------------------------------------------
// Scan phase C: per-block exclusive scan + block offset -> offsets, cursor.
// ---------------------------------------------------------------------------
__global__ __launch_bounds__(256) void final_scan_kernel(
    const int* __restrict__ cnt, const int* __restrict__ boff,
    int* __restrict__ offsets, int* __restrict__ cursor)
{
    __shared__ int sh[256];
    int t = threadIdx.x;
    int i = blockIdx.x * 256 + t;
    int v = (i < N_NODES) ? cnt[i] : 0;
    sh[t] = v;
    __syncthreads();
    for (int d = 1; d < 256; d <<= 1) {
        int u = (t >= d) ? sh[t - d] : 0;
        __syncthreads();
        sh[t] += u;
        __syncthreads();
    }
    int excl = sh[t] - v + boff[blockIdx.x];
    if (i < N_NODES) { offsets[i] = excl; cursor[i] = excl; }
    if (i == 0) offsets[N_NODES] = N_EDGES;
}

// ---------------------------------------------------------------------------
// Ticket scatter into CSR order. Stores {src, exp(e)} packed as int2 so the
// aggregation loop does ONE 8B broadcast load per edge.
// segment_max skipped: softmax is shift-invariant and |e| <= |a0|+|a1| is
// tiny, so exp() cannot overflow -- identical math to the reference.
// ---------------------------------------------------------------------------
__global__ __launch_bounds__(256) void scatter_kernel(
    const float* __restrict__ rel, const float* __restrict__ attn_e,
    const int* __restrict__ src, const int* __restrict__ dst,
    int* __restrict__ cursor, int2* __restrict__ edata)
{
    int e = blockIdx.x * 256 + threadIdx.x;
    if (e >= N_EDGES) return;
    float a0 = attn_e[0], a1 = attn_e[1];
    float2 r = ((const float2*)rel)[e];
    float sc = r.x * a0 + r.y * a1;
    sc = (sc > 0.f) ? sc : NEG_SLOPE * sc;
    float ev = __expf(sc);
    int d = dst[e];
    int pos = atomicAdd(&cursor[d], 1);        // avg 16 tickets/counter
    edata[pos] = make_int2(src[e], __float_as_int(ev));
}

// ---------------------------------------------------------------------------
// GEMM: g = bf16(feat @ W_neigh^T); out = feat @ W_self^T + (b_self+b_neigh)
// Weight columns in REGISTERS (lane o owns W[o][:], 128 VGPRs). Feat rows
// staged to LDS with coalesced float4 loads, then read back as same-address
// float4 LDS broadcasts (free, no bank conflict). g stored bf16: halves its
// write traffic AND halves the downstream gather bytes.
// ---------------------------------------------------------------------------
__global__ __launch_bounds__(256) void gemm_kernel(
    const float* __restrict__ feat, const float* __restrict__ W_self,
    const float* __restrict__ b_self, const float* __restrict__ W_neigh,
    const float* __restrict__ b_neigh, __hip_bfloat16* __restrict__ g,
    float* __restrict__ out)
{
    __shared__ float Wt[2][D][D + 1];          // transposed weights, padded
    __shared__ float fs[64 * D];               // 64 feat rows (16 KB)
    int tid = threadIdx.x;
    #pragma unroll
    for (int i = 0; i < 16; ++i) {
        int idx = tid + i * 256;               // coalesced global read
        int o = idx >> 6, k = idx & 63;
        Wt[0][k][o] = W_self[idx];
        Wt[1][k][o] = W_neigh[idx];
    }
    // stage 64 rows of feat, coalesced float4 (1024 float4s / 256 threads)
    {
        long base4 = (long)blockIdx.x * 1024;  // float4 index
        const float4* f4 = (const float4*)feat;
        float4* s4 = (float4*)fs;
        #pragma unroll
        for (int i = 0; i < 4; ++i) {
            int idx = tid + i * 256;
            if (base4 + idx < (long)N_NODES * D / 4) s4[idx] = f4[base4 + idx];
        }
    }
    __syncthreads();

    int lane = tid & 63;
    int wave = tid >> 6;
    float ws[D], wn[D];
    #pragma unroll
    for (int k = 0; k < D; ++k) {              // lanes read consecutive o:
        ws[k] = Wt[0][k][lane];                // conflict-free ds_read
        wn[k] = Wt[1][k][lane];
    }
    float bias = b_self[lane] + b_neigh[lane];

    int r0 = blockIdx.x * 64 + wave * 16;      // 16 rows per wave
    #pragma unroll 2
    for (int rr = 0; rr < 16; ++rr) {
        int r = r0 + rr;
        if (r >= N_NODES) break;
        const float4* frow = (const float4*)(fs + (wave * 16 + rr) * D);
        float accs = 0.f, accn = 0.f;
        #pragma unroll
        for (int k4 = 0; k4 < 16; ++k4) {
            float4 f = frow[k4];               // LDS broadcast (same addr)
            accs += f.x * ws[4*k4]   + f.y * ws[4*k4+1]
                  + f.z * ws[4*k4+2] + f.w * ws[4*k4+3];
            accn += f.x * wn[4*k4]   + f.y * wn[4*k4+1]
                  + f.z * wn[4*k4+2] + f.w * wn[4*k4+3];
        }
        out[(size_t)r * D + lane] = accs + bias;
        g[(size_t)r * D + lane] = __float2bfloat16(accn);
    }
}

// ---------------------------------------------------------------------------
// Aggregation: one wave per node, lane = feature. Edge loop unrolled x4 with
// batched independent loads (4 edata broadcasts + 4 bf16 row gathers in
// flight) to hide gather latency. Denominator computed in-wave. Zero atomics.
// ---------------------------------------------------------------------------
__global__ __launch_bounds__(256) void aggregate_kernel(
    const ushort* __restrict__ g, const int2* __restrict__ edata,
    const int* __restrict__ offsets, float* __restrict__ out)
{
    int v = blockIdx.x * 4 + (threadIdx.x >> 6);   // 25000*4 == N exactly
    int lane = threadIdx.x & 63;
    int lo = offsets[v], hi = offsets[v + 1];
    float acc = 0.f, sum = 0.f;
    int i = lo;
    for (; i + 4 <= hi; i += 4) {
        int2 e0 = edata[i];                        // 4 independent broadcasts
        int2 e1 = edata[i + 1];
        int2 e2 = edata[i + 2];
        int2 e3 = edata[i + 3];
        ushort u0 = g[(size_t)e0.x * D + lane];    // 4 gathers in flight
        ushort u1 = g[(size_t)e1.x * D + lane];
        ushort u2 = g[(size_t)e2.x * D + lane];
        ushort u3 = g[(size_t)e3.x * D + lane];
        float w0 = __int_as_float(e0.y), w1 = __int_as_float(e1.y);
        float w2 = __int_as_float(e2.y), w3 = __int_as_float(e3.y);
        acc += w0 * __uint_as_float((unsigned)u0 << 16);
        acc += w1 * __uint_as_float((unsigned)u1 << 16);
        acc += w2 * __uint_as_float((unsigned)u2 << 16);
        acc += w3 * __uint_as_float((unsigned)u3 << 16);
        sum += (w0 + w1) + (w2 + w3);
    }
    for (; i < hi; ++i) {
        int2 ed = edata[i];
        float w = __int_as_float(ed.y);
        acc += w * __uint_as_float((unsigned)g[(size_t)ed.x * D + lane] << 16);
        sum += w;
    }
    if (hi > lo) {
        size_t idx = (size_t)v * D + lane;
        out[idx] += acc / sum;
    }
    // zero-degree nodes: reference gives h_neigh = 0 -> out keeps self part
}

// ---------------------------------------------------------------------------
extern "C" void kernel_launch(void* const* d_in, const int* in_sizes, int n_in,
                              void* d_out, int out_size, void* d_ws, size_t ws_size,
                              hipStream_t stream) {
    const float* feat    = (const float*)d_in[0];
    const float* rel     = (const float*)d_in[1];
    const float* W_self  = (const float*)d_in[2];
    const float* b_self  = (const float*)d_in[3];
    const float* W_neigh = (const float*)d_in[4];
    const float* b_neigh = (const float*)d_in[5];
    const float* attn_e  = (const float*)d_in[6];
    const int*   src     = (const int*)d_in[7];
    const int*   dst     = (const int*)d_in[8];
    float* out = (float*)d_out;

    // workspace layout (~26.5 MB)
    __hip_bfloat16* g = (__hip_bfloat16*)d_ws;            // [N*D] bf16 12.8 MB
    int2* edata   = (int2*)((char*)d_ws + (size_t)N_NODES * D * 2); // [E] 12.8 MB
    int*  cnt     = (int*)(edata + N_EDGES);              // [N]
    int*  offsets = cnt + N_NODES;                        // [N+1]
    int*  cursor  = offsets + N_NODES + 1;                // [N]
    int*  bsum    = cursor + N_NODES;                     // [NB]
    int*  boff    = bsum + NB;                            // [NB]

    hipMemsetAsync(cnt, 0, N_NODES * sizeof(int), stream);

    hist_kernel<<<(N_EDGES / 4 + 255) / 256, 256, 0, stream>>>(
        (const int4*)dst, cnt);
    block_sum_kernel<<<NB, 256, 0, stream>>>(cnt, bsum);
    scan_bsum_kernel<<<1, 512, 0, stream>>>(bsum, boff);
    final_scan_kernel<<<NB, 256, 0, stream>>>(cnt, boff, offsets, cursor);
    scatter_kernel<<<(N_EDGES + 255) / 256, 256, 0, stream>>>(
        rel, attn_e, src, dst, cursor, edata);
    gemm_kernel<<<(N_NODES + 63) / 64, 256, 0, stream>>>(
        feat, W_self, b_self, W_neigh, b_neigh, g, out);
    aggregate_kernel<<<N_NODES / 4, 256, 0, stream>>>(
        (const ushort*)g, edata, offsets, out);
}

// Round 5
// 424.396 us; speedup vs baseline: 1.5315x; 1.5315x over previous
//
#include <hip/hip_runtime.h>
#include <hip/hip_bf16.h>

#define N_NODES 100000
#define N_EDGES 1600000
#define D 64
#define NEG_SLOPE 0.2f
#define NB ((N_NODES + 255) / 256)   // 391 scan blocks

// ---------------------------------------------------------------------------
// Kernel 1: histogram of edges per destination node (int4-vectorized reads).
// ---------------------------------------------------------------------------
__global__ __launch_bounds__(256) void hist_kernel(
    const int4* __restrict__ dst4, int* __restrict__ cnt)
{
    int i = blockIdx.x * 256 + threadIdx.x;
    if (i < N_EDGES / 4) {                       // 1.6M % 4 == 0
        int4 d = dst4[i];
        atomicAdd(&cnt[d.x], 1);
        atomicAdd(&cnt[d.y], 1);
        atomicAdd(&cnt[d.z], 1);
        atomicAdd(&cnt[d.w], 1);
    }
}

// ---------------------------------------------------------------------------
// Scan phase A: per-block (256-wide) sums of cnt.
// ---------------------------------------------------------------------------
__global__ __launch_bounds__(256) void block_sum_kernel(
    const int* __restrict__ cnt, int* __restrict__ bsum)
{
    int i = blockIdx.x * 256 + threadIdx.x;
    int v = (i < N_NODES) ? cnt[i] : 0;
    #pragma unroll
    for (int o = 32; o > 0; o >>= 1) v += __shfl_down(v, o);
    __shared__ int ws[4];
    if ((threadIdx.x & 63) == 0) ws[threadIdx.x >> 6] = v;
    __syncthreads();
    if (threadIdx.x == 0) bsum[blockIdx.x] = ws[0] + ws[1] + ws[2] + ws[3];
}

// ---------------------------------------------------------------------------
// Scan phase B: exclusive scan of the 391 block sums (single small block).
// ---------------------------------------------------------------------------
__global__ __launch_bounds__(512) void scan_bsum_kernel(
    const int* __restrict__ bsum, int* __restrict__ boff)
{
    __shared__ int sh[512];
    int t = threadIdx.x;
    int v = (t < NB) ? bsum[t] : 0;
    sh[t] = v;
    __syncthreads();
    for (int d = 1; d < 512; d <<= 1) {
        int u = (t >= d) ? sh[t - d] : 0;
        __syncthreads();
        sh[t] += u;
        __syncthreads();
    }
    if (t < NB) boff[t] = sh[t] - v;          // exclusive prefix
}

// ---------------------------------------------------------------------------
// Scan phase C: per-block exclusive scan + block offset -> offsets, cursor.
// ---------------------------------------------------------------------------
__global__ __launch_bounds__(256) void final_scan_kernel(
    const int* __restrict__ cnt, const int* __restrict__ boff,
    int* __restrict__ offsets, int* __restrict__ cursor)
{
    __shared__ int sh[256];
    int t = threadIdx.x;
    int i = blockIdx.x * 256 + t;
    int v = (i < N_NODES) ? cnt[i] : 0;
    sh[t] = v;
    __syncthreads();
    for (int d = 1; d < 256; d <<= 1) {
        int u = (t >= d) ? sh[t - d] : 0;
        __syncthreads();
        sh[t] += u;
        __syncthreads();
    }
    int excl = sh[t] - v + boff[blockIdx.x];
    if (i < N_NODES) { offsets[i] = excl; cursor[i] = excl; }
    if (i == 0) offsets[N_NODES] = N_EDGES;
}

// ---------------------------------------------------------------------------
// Ticket scatter into CSR order. Stores {src, exp(e)} packed as int2 so the
// aggregation loop does ONE 8B broadcast load per edge.
// segment_max skipped: softmax is shift-invariant and |e| <= |a0|+|a1| is
// tiny, so exp() cannot overflow -- identical math to the reference.
// ---------------------------------------------------------------------------
__global__ __launch_bounds__(256) void scatter_kernel(
    const float* __restrict__ rel, const float* __restrict__ attn_e,
    const int* __restrict__ src, const int* __restrict__ dst,
    int* __restrict__ cursor, int2* __restrict__ edata)
{
    int e = blockIdx.x * 256 + threadIdx.x;
    if (e >= N_EDGES) return;
    float a0 = attn_e[0], a1 = attn_e[1];
    float2 r = ((const float2*)rel)[e];
    float sc = r.x * a0 + r.y * a1;
    sc = (sc > 0.f) ? sc : NEG_SLOPE * sc;
    float ev = __expf(sc);
    int d = dst[e];
    int pos = atomicAdd(&cursor[d], 1);        // avg 16 tickets/counter
    edata[pos] = make_int2(src[e], __float_as_int(ev));
}

// ---------------------------------------------------------------------------
// GEMM kernels, SPLIT so each holds only ONE 64-register weight set
// (round-4 fused version hit the 256-VGPR cap and spilled to scratch:
// FETCH/WRITE inflated 8x). Lane o owns W[o][:] in 64 VGPRs; feat rows are
// staged to LDS coalesced, then read as same-address float4 broadcasts.
// ---------------------------------------------------------------------------
__global__ __launch_bounds__(256) void gemm_self_kernel(
    const float* __restrict__ feat, const float* __restrict__ W_self,
    const float* __restrict__ b_self, const float* __restrict__ b_neigh,
    float* __restrict__ out)
{
    __shared__ float Wt[D][D + 1];             // transposed weights, padded
    __shared__ float fs[64 * D];               // 64 feat rows (16 KB)
    int tid = threadIdx.x;
    #pragma unroll
    for (int i = 0; i < 16; ++i) {
        int idx = tid + i * 256;               // coalesced global read
        Wt[idx & 63][idx >> 6] = W_self[idx];
    }
    {
        long base4 = (long)blockIdx.x * 1024;  // float4 index
        const float4* f4 = (const float4*)feat;
        float4* s4 = (float4*)fs;
        #pragma unroll
        for (int i = 0; i < 4; ++i) {
            int idx = tid + i * 256;
            if (base4 + idx < (long)N_NODES * D / 4) s4[idx] = f4[base4 + idx];
        }
    }
    __syncthreads();

    int lane = tid & 63;
    int wave = tid >> 6;
    float w[D];
    #pragma unroll
    for (int k = 0; k < D; ++k) w[k] = Wt[k][lane];   // conflict-free
    float bias = b_self[lane] + b_neigh[lane];

    int r0 = blockIdx.x * 64 + wave * 16;
    #pragma unroll 1
    for (int rr = 0; rr < 16; ++rr) {
        int r = r0 + rr;
        if (r >= N_NODES) break;
        const float4* frow = (const float4*)(fs + (wave * 16 + rr) * D);
        float acc = 0.f;
        #pragma unroll
        for (int k4 = 0; k4 < 16; ++k4) {
            float4 f = frow[k4];               // LDS broadcast (same addr)
            acc += f.x * w[4*k4]   + f.y * w[4*k4+1]
                 + f.z * w[4*k4+2] + f.w * w[4*k4+3];
        }
        out[(size_t)r * D + lane] = acc + bias;
    }
}

__global__ __launch_bounds__(256) void gemm_neigh_kernel(
    const float* __restrict__ feat, const float* __restrict__ W_neigh,
    __hip_bfloat16* __restrict__ g)
{
    __shared__ float Wt[D][D + 1];
    __shared__ float fs[64 * D];
    int tid = threadIdx.x;
    #pragma unroll
    for (int i = 0; i < 16; ++i) {
        int idx = tid + i * 256;
        Wt[idx & 63][idx >> 6] = W_neigh[idx];
    }
    {
        long base4 = (long)blockIdx.x * 1024;
        const float4* f4 = (const float4*)feat;
        float4* s4 = (float4*)fs;
        #pragma unroll
        for (int i = 0; i < 4; ++i) {
            int idx = tid + i * 256;
            if (base4 + idx < (long)N_NODES * D / 4) s4[idx] = f4[base4 + idx];
        }
    }
    __syncthreads();

    int lane = tid & 63;
    int wave = tid >> 6;
    float w[D];
    #pragma unroll
    for (int k = 0; k < D; ++k) w[k] = Wt[k][lane];

    int r0 = blockIdx.x * 64 + wave * 16;
    #pragma unroll 1
    for (int rr = 0; rr < 16; ++rr) {
        int r = r0 + rr;
        if (r >= N_NODES) break;
        const float4* frow = (const float4*)(fs + (wave * 16 + rr) * D);
        float acc = 0.f;
        #pragma unroll
        for (int k4 = 0; k4 < 16; ++k4) {
            float4 f = frow[k4];
            acc += f.x * w[4*k4]   + f.y * w[4*k4+1]
                 + f.z * w[4*k4+2] + f.w * w[4*k4+3];
        }
        g[(size_t)r * D + lane] = __float2bfloat16(acc);
    }
}

// ---------------------------------------------------------------------------
// Aggregation: one wave per node, lane = feature. Edge loop unrolled x4 with
// batched independent loads (4 edata broadcasts + 4 bf16 row gathers in
// flight) to hide gather latency. Denominator computed in-wave. Zero atomics.
// ---------------------------------------------------------------------------
__global__ __launch_bounds__(256) void aggregate_kernel(
    const ushort* __restrict__ g, const int2* __restrict__ edata,
    const int* __restrict__ offsets, float* __restrict__ out)
{
    int v = blockIdx.x * 4 + (threadIdx.x >> 6);   // 25000*4 == N exactly
    int lane = threadIdx.x & 63;
    int lo = offsets[v], hi = offsets[v + 1];
    float acc = 0.f, sum = 0.f;
    int i = lo;
    for (; i + 4 <= hi; i += 4) {
        int2 e0 = edata[i];                        // 4 independent broadcasts
        int2 e1 = edata[i + 1];
        int2 e2 = edata[i + 2];
        int2 e3 = edata[i + 3];
        ushort u0 = g[(size_t)e0.x * D + lane];    // 4 gathers in flight
        ushort u1 = g[(size_t)e1.x * D + lane];
        ushort u2 = g[(size_t)e2.x * D + lane];
        ushort u3 = g[(size_t)e3.x * D + lane];
        float w0 = __int_as_float(e0.y), w1 = __int_as_float(e1.y);
        float w2 = __int_as_float(e2.y), w3 = __int_as_float(e3.y);
        acc += w0 * __uint_as_float((unsigned)u0 << 16);
        acc += w1 * __uint_as_float((unsigned)u1 << 16);
        acc += w2 * __uint_as_float((unsigned)u2 << 16);
        acc += w3 * __uint_as_float((unsigned)u3 << 16);
        sum += (w0 + w1) + (w2 + w3);
    }
    for (; i < hi; ++i) {
        int2 ed = edata[i];
        float w = __int_as_float(ed.y);
        acc += w * __uint_as_float((unsigned)g[(size_t)ed.x * D + lane] << 16);
        sum += w;
    }
    if (hi > lo) {
        size_t idx = (size_t)v * D + lane;
        out[idx] += acc / sum;
    }
    // zero-degree nodes: reference gives h_neigh = 0 -> out keeps self part
}

// ---------------------------------------------------------------------------
extern "C" void kernel_launch(void* const* d_in, const int* in_sizes, int n_in,
                              void* d_out, int out_size, void* d_ws, size_t ws_size,
                              hipStream_t stream) {
    const float* feat    = (const float*)d_in[0];
    const float* rel     = (const float*)d_in[1];
    const float* W_self  = (const float*)d_in[2];
    const float* b_self  = (const float*)d_in[3];
    const float* W_neigh = (const float*)d_in[4];
    const float* b_neigh = (const float*)d_in[5];
    const float* attn_e  = (const float*)d_in[6];
    const int*   src     = (const int*)d_in[7];
    const int*   dst     = (const int*)d_in[8];
    float* out = (float*)d_out;

    // workspace layout (~26.5 MB)
    __hip_bfloat16* g = (__hip_bfloat16*)d_ws;            // [N*D] bf16 12.8 MB
    int2* edata   = (int2*)((char*)d_ws + (size_t)N_NODES * D * 2); // [E] 12.8 MB
    int*  cnt     = (int*)(edata + N_EDGES);              // [N]
    int*  offsets = cnt + N_NODES;                        // [N+1]
    int*  cursor  = offsets + N_NODES + 1;                // [N]
    int*  bsum    = cursor + N_NODES;                     // [NB]
    int*  boff    = bsum + NB;                            // [NB]

    hipMemsetAsync(cnt, 0, N_NODES * sizeof(int), stream);

    hist_kernel<<<(N_EDGES / 4 + 255) / 256, 256, 0, stream>>>(
        (const int4*)dst, cnt);
    block_sum_kernel<<<NB, 256, 0, stream>>>(cnt, bsum);
    scan_bsum_kernel<<<1, 512, 0, stream>>>(bsum, boff);
    final_scan_kernel<<<NB, 256, 0, stream>>>(cnt, boff, offsets, cursor);
    scatter_kernel<<<(N_EDGES + 255) / 256, 256, 0, stream>>>(
        rel, attn_e, src, dst, cursor, edata);
    gemm_self_kernel<<<(N_NODES + 63) / 64, 256, 0, stream>>>(
        feat, W_self, b_self, b_neigh, out);
    gemm_neigh_kernel<<<(N_NODES + 63) / 64, 256, 0, stream>>>(
        feat, W_neigh, g);
    aggregate_kernel<<<N_NODES / 4, 256, 0, stream>>>(
        (const ushort*)g, edata, offsets, out);
}

// Round 6
// 282.838 us; speedup vs baseline: 2.2980x; 1.5005x over previous
//
#include <hip/hip_runtime.h>
#include <hip/hip_bf16.h>

#define N_NODES 100000
#define N_EDGES 1600000
#define D 64
#define NEG_SLOPE 0.2f

#define BSHIFT 10                                  // bucket = dst >> 10
#define BNODES 1024                                // nodes per bucket
#define NBUCK ((N_NODES + BNODES - 1) >> BSHIFT)   // 98
#define BUCKET_CAP 17408   // mean 16384, sigma ~127 -> 8-sigma headroom
#define P1_EPB 4096        // edges per binning block
#define P1_IT (P1_EPB / 256)                       // 16 edges/thread

// ---------------------------------------------------------------------------
// Pass 1: bin edges by coarse dst bucket, LDS-staged so ALL global writes are
// coalesced runs (round-5 scatter wrote 100 MB of dirty partial lines for a
// 12.8 MB array -- write-line-granularity bound). Entry: {x = (src<<15)|wcode
// (bf16 weight, sign dropped), y = dst}.
// segment_max skipped: softmax is shift-invariant and |e| <= |a0|+|a1| is
// tiny, so exp() cannot overflow -- identical math to the reference.
// ---------------------------------------------------------------------------
__global__ __launch_bounds__(256) void binning_kernel(
    const float2* __restrict__ rel, const float* __restrict__ attn_e,
    const int* __restrict__ src, const int* __restrict__ dst,
    int* __restrict__ bucket_cursor, uint2* __restrict__ binned)
{
    __shared__ uint2 staged1[P1_EPB];   // arrival order      (32 KB)
    __shared__ uint2 staged2[P1_EPB];   // bucket-sorted      (32 KB)
    __shared__ int cnt[NBUCK];
    __shared__ int excl[NBUCK];
    __shared__ int chunkbase[NBUCK];

    int tid = threadIdx.x;
    int e0 = blockIdx.x * P1_EPB;
    int n = min(P1_EPB, N_EDGES - e0);

    for (int b = tid; b < NBUCK; b += 256) cnt[b] = 0;
    __syncthreads();

    float a0 = attn_e[0], a1 = attn_e[1];

    int myslot[P1_IT];                  // fixed-index -> stays in VGPRs
    #pragma unroll
    for (int j = 0; j < P1_IT; ++j) {
        int i = tid + j * 256;
        if (i < n) {
            int e = e0 + i;
            float2 r = rel[e];
            float sc = r.x * a0 + r.y * a1;
            sc = (sc > 0.f) ? sc : NEG_SLOPE * sc;
            float ev = __expf(sc);
            unsigned u = __float_as_uint(ev) + 0x8000u;     // RNE to bf16
            unsigned wcode = (u >> 16) & 0x7FFFu;           // drop sign (ev>0)
            unsigned s = (unsigned)src[e];
            unsigned d = (unsigned)dst[e];
            staged1[i] = make_uint2((s << 15) | wcode, d);
            myslot[j] = atomicAdd(&cnt[d >> BSHIFT], 1);    // local ticket
        }
    }
    __syncthreads();
    if (tid == 0) {                     // 98-entry serial scan: trivial
        int run = 0;
        for (int b = 0; b < NBUCK; ++b) { excl[b] = run; run += cnt[b]; }
    }
    __syncthreads();
    #pragma unroll
    for (int j = 0; j < P1_IT; ++j) {   // LDS scatter into bucket order
        int i = tid + j * 256;
        if (i < n) {
            uint2 v = staged1[i];
            staged2[excl[v.y >> BSHIFT] + myslot[j]] = v;
        }
    }
    if (tid < NBUCK)                    // reserve contiguous global chunks
        chunkbase[tid] = atomicAdd(&bucket_cursor[tid], cnt[tid]);
    __syncthreads();
    for (int i = tid; i < n; i += 256) {   // coalesced runs per bucket chunk
        uint2 v = staged2[i];
        int b = (int)(v.y >> BSHIFT);
        binned[(size_t)b * BUCKET_CAP + chunkbase[b] + (i - excl[b])] = v;
    }
}

// ---------------------------------------------------------------------------
// Pass 2: one block per bucket. LDS histogram -> LDS scan -> write offsets
// (replaces the old hist + 3 scan kernels) -> LDS scatter of packed values
// -> one coalesced flush into the bucket's contiguous CSR range.
// ---------------------------------------------------------------------------
__global__ __launch_bounds__(256) void csr_kernel(
    const int* __restrict__ bucket_cursor, const uint2* __restrict__ binned,
    int* __restrict__ offsets, unsigned* __restrict__ edata)
{
    __shared__ unsigned vals[BUCKET_CAP];   // 69.6 KB
    __shared__ int hist[BNODES];
    __shared__ int nexcl[BNODES];
    __shared__ int cur[BNODES];
    __shared__ int bc[NBUCK];
    __shared__ int sh[256];
    __shared__ int base_sh;

    int b = blockIdx.x;
    int tid = threadIdx.x;

    if (tid < NBUCK) bc[tid] = bucket_cursor[tid];
    for (int j = tid; j < BNODES; j += 256) { hist[j] = 0; cur[j] = 0; }
    __syncthreads();
    if (tid == 0) {
        int s = 0;
        for (int i = 0; i < b; ++i) s += bc[i];
        base_sh = s;
    }
    __syncthreads();
    int count = bc[b];
    int base = base_sh;
    const uint2* bin = binned + (size_t)b * BUCKET_CAP;

    for (int i = tid; i < count; i += 256)
        atomicAdd(&hist[bin[i].y & (BNODES - 1)], 1);
    __syncthreads();

    // scan 1024 histogram bins: 4/thread + Hillis-Steele over 256 partials
    int h0 = hist[4 * tid], h1 = hist[4 * tid + 1];
    int h2 = hist[4 * tid + 2], h3 = hist[4 * tid + 3];
    int p = h0 + h1 + h2 + h3;
    sh[tid] = p;
    __syncthreads();
    for (int d = 1; d < 256; d <<= 1) {
        int u = (tid >= d) ? sh[tid - d] : 0;
        __syncthreads();
        sh[tid] += u;
        __syncthreads();
    }
    int run = sh[tid] - p;
    nexcl[4 * tid] = run;     run += h0;
    nexcl[4 * tid + 1] = run; run += h1;
    nexcl[4 * tid + 2] = run; run += h2;
    nexcl[4 * tid + 3] = run;
    __syncthreads();

    int node0 = b << BSHIFT;
    for (int j = tid; j < BNODES; j += 256) {
        int node = node0 + j;
        if (node < N_NODES) offsets[node] = base + nexcl[j];
    }
    if (b == NBUCK - 1 && tid == 0) offsets[N_NODES] = N_EDGES;

    for (int i = tid; i < count; i += 256) {      // LDS scatter
        uint2 e = bin[i];
        int d = e.y & (BNODES - 1);
        int t = atomicAdd(&cur[d], 1);
        vals[nexcl[d] + t] = e.x;
    }
    __syncthreads();
    for (int i = tid; i < count; i += 256)        // coalesced flush
        edata[base + i] = vals[i];
}

// ---------------------------------------------------------------------------
// GEMM kernels, SPLIT so each holds only ONE 64-register weight set (fused
// version hit the 256-VGPR cap and spilled: FETCH/WRITE inflated 8x).
// ---------------------------------------------------------------------------
__global__ __launch_bounds__(256) void gemm_self_kernel(
    const float* __restrict__ feat, const float* __restrict__ W_self,
    const float* __restrict__ b_self, const float* __restrict__ b_neigh,
    float* __restrict__ out)
{
    __shared__ float Wt[D][D + 1];
    __shared__ float fs[64 * D];
    int tid = threadIdx.x;
    #pragma unroll
    for (int i = 0; i < 16; ++i) {
        int idx = tid + i * 256;
        Wt[idx & 63][idx >> 6] = W_self[idx];
    }
    {
        long base4 = (long)blockIdx.x * 1024;
        const float4* f4 = (const float4*)feat;
        float4* s4 = (float4*)fs;
        #pragma unroll
        for (int i = 0; i < 4; ++i) {
            int idx = tid + i * 256;
            if (base4 + idx < (long)N_NODES * D / 4) s4[idx] = f4[base4 + idx];
        }
    }
    __syncthreads();

    int lane = tid & 63;
    int wave = tid >> 6;
    float w[D];
    #pragma unroll
    for (int k = 0; k < D; ++k) w[k] = Wt[k][lane];
    float bias = b_self[lane] + b_neigh[lane];

    int r0 = blockIdx.x * 64 + wave * 16;
    #pragma unroll 1
    for (int rr = 0; rr < 16; ++rr) {
        int r = r0 + rr;
        if (r >= N_NODES) break;
        const float4* frow = (const float4*)(fs + (wave * 16 + rr) * D);
        float acc = 0.f;
        #pragma unroll
        for (int k4 = 0; k4 < 16; ++k4) {
            float4 f = frow[k4];
            acc += f.x * w[4*k4]   + f.y * w[4*k4+1]
                 + f.z * w[4*k4+2] + f.w * w[4*k4+3];
        }
        out[(size_t)r * D + lane] = acc + bias;
    }
}

__global__ __launch_bounds__(256) void gemm_neigh_kernel(
    const float* __restrict__ feat, const float* __restrict__ W_neigh,
    __hip_bfloat16* __restrict__ g)
{
    __shared__ float Wt[D][D + 1];
    __shared__ float fs[64 * D];
    int tid = threadIdx.x;
    #pragma unroll
    for (int i = 0; i < 16; ++i) {
        int idx = tid + i * 256;
        Wt[idx & 63][idx >> 6] = W_neigh[idx];
    }
    {
        long base4 = (long)blockIdx.x * 1024;
        const float4* f4 = (const float4*)feat;
        float4* s4 = (float4*)fs;
        #pragma unroll
        for (int i = 0; i < 4; ++i) {
            int idx = tid + i * 256;
            if (base4 + idx < (long)N_NODES * D / 4) s4[idx] = f4[base4 + idx];
        }
    }
    __syncthreads();

    int lane = tid & 63;
    int wave = tid >> 6;
    float w[D];
    #pragma unroll
    for (int k = 0; k < D; ++k) w[k] = Wt[k][lane];

    int r0 = blockIdx.x * 64 + wave * 16;
    #pragma unroll 1
    for (int rr = 0; rr < 16; ++rr) {
        int r = r0 + rr;
        if (r >= N_NODES) break;
        const float4* frow = (const float4*)(fs + (wave * 16 + rr) * D);
        float acc = 0.f;
        #pragma unroll
        for (int k4 = 0; k4 < 16; ++k4) {
            float4 f = frow[k4];
            acc += f.x * w[4*k4]   + f.y * w[4*k4+1]
                 + f.z * w[4*k4+2] + f.w * w[4*k4+3];
        }
        g[(size_t)r * D + lane] = __float2bfloat16(acc);
    }
}

// ---------------------------------------------------------------------------
// Aggregation: one wave per node, lane = feature. Edge loop unrolled x4 with
// batched independent loads. 4B packed edata: {src:17 | wcode:15}.
// Denominator computed in-wave. Zero atomics.
// ---------------------------------------------------------------------------
__global__ __launch_bounds__(256) void aggregate_kernel(
    const ushort* __restrict__ g, const unsigned* __restrict__ edata,
    const int* __restrict__ offsets, float* __restrict__ out)
{
    int v = blockIdx.x * 4 + (threadIdx.x >> 6);   // 25000*4 == N exactly
    int lane = threadIdx.x & 63;
    int lo = offsets[v], hi = offsets[v + 1];
    float acc = 0.f, sum = 0.f;
    int i = lo;
    for (; i + 4 <= hi; i += 4) {
        unsigned p0 = edata[i],     p1 = edata[i + 1];
        unsigned p2 = edata[i + 2], p3 = edata[i + 3];
        ushort u0 = g[(size_t)(p0 >> 15) * D + lane];   // 4 gathers in flight
        ushort u1 = g[(size_t)(p1 >> 15) * D + lane];
        ushort u2 = g[(size_t)(p2 >> 15) * D + lane];
        ushort u3 = g[(size_t)(p3 >> 15) * D + lane];
        float w0 = __uint_as_float((p0 & 0x7FFFu) << 16);
        float w1 = __uint_as_float((p1 & 0x7FFFu) << 16);
        float w2 = __uint_as_float((p2 & 0x7FFFu) << 16);
        float w3 = __uint_as_float((p3 & 0x7FFFu) << 16);
        acc += w0 * __uint_as_float((unsigned)u0 << 16);
        acc += w1 * __uint_as_float((unsigned)u1 << 16);
        acc += w2 * __uint_as_float((unsigned)u2 << 16);
        acc += w3 * __uint_as_float((unsigned)u3 << 16);
        sum += (w0 + w1) + (w2 + w3);
    }
    for (; i < hi; ++i) {
        unsigned p = edata[i];
        float w = __uint_as_float((p & 0x7FFFu) << 16);
        acc += w * __uint_as_float((unsigned)g[(size_t)(p >> 15) * D + lane] << 16);
        sum += w;
    }
    if (hi > lo) {
        size_t idx = (size_t)v * D + lane;
        out[idx] += acc / sum;
    }
    // zero-degree nodes: reference gives h_neigh = 0 -> out keeps self part
}

// ---------------------------------------------------------------------------
extern "C" void kernel_launch(void* const* d_in, const int* in_sizes, int n_in,
                              void* d_out, int out_size, void* d_ws, size_t ws_size,
                              hipStream_t stream) {
    const float* feat    = (const float*)d_in[0];
    const float* rel     = (const float*)d_in[1];
    const float* W_self  = (const float*)d_in[2];
    const float* b_self  = (const float*)d_in[3];
    const float* W_neigh = (const float*)d_in[4];
    const float* b_neigh = (const float*)d_in[5];
    const float* attn_e  = (const float*)d_in[6];
    const int*   src     = (const int*)d_in[7];
    const int*   dst     = (const int*)d_in[8];
    float* out = (float*)d_out;

    // workspace layout (~33.3 MB)
    uint2* binned = (uint2*)d_ws;                               // 13.65 MB
    __hip_bfloat16* g = (__hip_bfloat16*)(binned + (size_t)NBUCK * BUCKET_CAP); // 12.8 MB
    unsigned* edata = (unsigned*)((char*)g + (size_t)N_NODES * D * 2);  // 6.4 MB
    int* offsets = (int*)(edata + N_EDGES);                     // [N+1]
    int* bucket_cursor = offsets + N_NODES + 1;                 // [NBUCK]

    hipMemsetAsync(bucket_cursor, 0, NBUCK * sizeof(int), stream);

    binning_kernel<<<(N_EDGES + P1_EPB - 1) / P1_EPB, 256, 0, stream>>>(
        (const float2*)rel, attn_e, src, dst, bucket_cursor, binned);
    csr_kernel<<<NBUCK, 256, 0, stream>>>(
        bucket_cursor, binned, offsets, edata);
    gemm_self_kernel<<<(N_NODES + 63) / 64, 256, 0, stream>>>(
        feat, W_self, b_self, b_neigh, out);
    gemm_neigh_kernel<<<(N_NODES + 63) / 64, 256, 0, stream>>>(
        feat, W_neigh, g);
    aggregate_kernel<<<N_NODES / 4, 256, 0, stream>>>(
        (const ushort*)g, edata, offsets, out);
}

// Round 7
// 260.838 us; speedup vs baseline: 2.4918x; 1.0843x over previous
//
#include <hip/hip_runtime.h>
#include <hip/hip_bf16.h>

#define N_NODES 100000
#define N_EDGES 1600000
#define D 64
#define NEG_SLOPE 0.2f

#define BSHIFT 10                                  // bucket = dst >> 10
#define BNODES 1024                                // nodes per bucket
#define NBUCK ((N_NODES + BNODES - 1) >> BSHIFT)   // 98
#define BUCKET_CAP 17408   // mean 16384, sigma ~127 -> 8-sigma headroom
#define P1_EPB 4096        // edges per binning block
#define P1_IT (P1_EPB / 256)                       // 16 edges/thread

// ---------------------------------------------------------------------------
// Pass 1: bin edges by coarse dst bucket, LDS-staged so ALL global writes are
// coalesced runs (direct scatter wrote 100 MB of dirty partial lines for a
// 12.8 MB array -- write-line-granularity bound). Entry: {x = (src<<15)|wcode
// (bf16 weight, sign dropped), y = dst}.
// segment_max skipped: softmax is shift-invariant and |e| <= |a0|+|a1| is
// tiny, so exp() cannot overflow -- identical math to the reference.
// ---------------------------------------------------------------------------
__global__ __launch_bounds__(256) void binning_kernel(
    const float2* __restrict__ rel, const float* __restrict__ attn_e,
    const int* __restrict__ src, const int* __restrict__ dst,
    int* __restrict__ bucket_cursor, uint2* __restrict__ binned)
{
    __shared__ uint2 staged1[P1_EPB];   // arrival order      (32 KB)
    __shared__ uint2 staged2[P1_EPB];   // bucket-sorted      (32 KB)
    __shared__ int cnt[NBUCK];
    __shared__ int excl[NBUCK];
    __shared__ int chunkbase[NBUCK];

    int tid = threadIdx.x;
    int e0 = blockIdx.x * P1_EPB;
    int n = min(P1_EPB, N_EDGES - e0);

    for (int b = tid; b < NBUCK; b += 256) cnt[b] = 0;
    __syncthreads();

    float a0 = attn_e[0], a1 = attn_e[1];

    int myslot[P1_IT];                  // fixed-index -> stays in VGPRs
    #pragma unroll
    for (int j = 0; j < P1_IT; ++j) {
        int i = tid + j * 256;
        if (i < n) {
            int e = e0 + i;
            float2 r = rel[e];
            float sc = r.x * a0 + r.y * a1;
            sc = (sc > 0.f) ? sc : NEG_SLOPE * sc;
            float ev = __expf(sc);
            unsigned u = __float_as_uint(ev) + 0x8000u;     // RNE to bf16
            unsigned wcode = (u >> 16) & 0x7FFFu;           // drop sign (ev>0)
            unsigned s = (unsigned)src[e];
            unsigned d = (unsigned)dst[e];
            staged1[i] = make_uint2((s << 15) | wcode, d);
            myslot[j] = atomicAdd(&cnt[d >> BSHIFT], 1);    // local ticket
        }
    }
    __syncthreads();
    if (tid == 0) {                     // 98-entry serial scan: trivial
        int run = 0;
        for (int b = 0; b < NBUCK; ++b) { excl[b] = run; run += cnt[b]; }
    }
    __syncthreads();
    #pragma unroll
    for (int j = 0; j < P1_IT; ++j) {   // LDS scatter into bucket order
        int i = tid + j * 256;
        if (i < n) {
            uint2 v = staged1[i];
            staged2[excl[v.y >> BSHIFT] + myslot[j]] = v;
        }
    }
    if (tid < NBUCK)                    // reserve contiguous global chunks
        chunkbase[tid] = atomicAdd(&bucket_cursor[tid], cnt[tid]);
    __syncthreads();
    for (int i = tid; i < n; i += 256) {   // coalesced runs per bucket chunk
        uint2 v = staged2[i];
        int b = (int)(v.y >> BSHIFT);
        binned[(size_t)b * BUCKET_CAP + chunkbase[b] + (i - excl[b])] = v;
    }
}

// ---------------------------------------------------------------------------
// Pass 2: one block per bucket, 1024 THREADS (only 98 blocks exist -- round-6
// ran 256 threads and underused the CU). LDS histogram -> LDS scan -> write
// offsets -> LDS scatter of packed values -> coalesced flush into the
// bucket's contiguous CSR range.
// ---------------------------------------------------------------------------
__global__ __launch_bounds__(1024) void csr_kernel(
    const int* __restrict__ bucket_cursor, const uint2* __restrict__ binned,
    int* __restrict__ offsets, unsigned* __restrict__ edata)
{
    __shared__ unsigned vals[BUCKET_CAP];   // 69.6 KB
    __shared__ int hist[BNODES];
    __shared__ int nexcl[BNODES];
    __shared__ int cur[BNODES];
    __shared__ int bc[NBUCK];
    __shared__ int base_sh;

    int b = blockIdx.x;
    int tid = threadIdx.x;

    if (tid < NBUCK) bc[tid] = bucket_cursor[tid];
    hist[tid] = 0;                      // 1024 threads cover BNODES exactly
    cur[tid] = 0;
    __syncthreads();
    if (tid == 0) {
        int s = 0;
        for (int i = 0; i < b; ++i) s += bc[i];
        base_sh = s;
    }
    __syncthreads();
    int count = bc[b];
    int base = base_sh;
    const uint2* bin = binned + (size_t)b * BUCKET_CAP;

    for (int i = tid; i < count; i += 1024)
        atomicAdd(&hist[bin[i].y & (BNODES - 1)], 1);
    __syncthreads();

    // inclusive Hillis-Steele over 1024 bins, one bin per thread
    int h = hist[tid];
    nexcl[tid] = h;
    __syncthreads();
    for (int d = 1; d < BNODES; d <<= 1) {
        int u = (tid >= d) ? nexcl[tid - d] : 0;
        __syncthreads();
        nexcl[tid] += u;
        __syncthreads();
    }
    int excl = nexcl[tid] - h;          // exclusive prefix
    __syncthreads();
    nexcl[tid] = excl;
    __syncthreads();

    int node = (b << BSHIFT) + tid;
    if (node < N_NODES) offsets[node] = base + excl;
    if (b == NBUCK - 1 && tid == 0) offsets[N_NODES] = N_EDGES;

    for (int i = tid; i < count; i += 1024) {     // LDS scatter
        uint2 e = bin[i];
        int d = e.y & (BNODES - 1);
        int t = atomicAdd(&cur[d], 1);
        vals[nexcl[d] + t] = e.x;
    }
    __syncthreads();
    for (int i = tid; i < count; i += 1024)       // coalesced flush
        edata[base + i] = vals[i];
}

// ---------------------------------------------------------------------------
// GEMM kernels, SPLIT so each holds only ONE 64-register weight set (fused
// version hit the 256-VGPR cap and spilled: FETCH/WRITE inflated 8x).
// ---------------------------------------------------------------------------
__global__ __launch_bounds__(256) void gemm_self_kernel(
    const float* __restrict__ feat, const float* __restrict__ W_self,
    const float* __restrict__ b_self, const float* __restrict__ b_neigh,
    float* __restrict__ out)
{
    __shared__ float Wt[D][D + 1];
    __shared__ float fs[64 * D];
    int tid = threadIdx.x;
    #pragma unroll
    for (int i = 0; i < 16; ++i) {
        int idx = tid + i * 256;
        Wt[idx & 63][idx >> 6] = W_self[idx];
    }
    {
        long base4 = (long)blockIdx.x * 1024;
        const float4* f4 = (const float4*)feat;
        float4* s4 = (float4*)fs;
        #pragma unroll
        for (int i = 0; i < 4; ++i) {
            int idx = tid + i * 256;
            if (base4 + idx < (long)N_NODES * D / 4) s4[idx] = f4[base4 + idx];
        }
    }
    __syncthreads();

    int lane = tid & 63;
    int wave = tid >> 6;
    float w[D];
    #pragma unroll
    for (int k = 0; k < D; ++k) w[k] = Wt[k][lane];
    float bias = b_self[lane] + b_neigh[lane];

    int r0 = blockIdx.x * 64 + wave * 16;
    #pragma unroll 1
    for (int rr = 0; rr < 16; ++rr) {
        int r = r0 + rr;
        if (r >= N_NODES) break;
        const float4* frow = (const float4*)(fs + (wave * 16 + rr) * D);
        float acc = 0.f;
        #pragma unroll
        for (int k4 = 0; k4 < 16; ++k4) {
            float4 f = frow[k4];
            acc += f.x * w[4*k4]   + f.y * w[4*k4+1]
                 + f.z * w[4*k4+2] + f.w * w[4*k4+3];
        }
        out[(size_t)r * D + lane] = acc + bias;
    }
}

__global__ __launch_bounds__(256) void gemm_neigh_kernel(
    const float* __restrict__ feat, const float* __restrict__ W_neigh,
    __hip_bfloat16* __restrict__ g)
{
    __shared__ float Wt[D][D + 1];
    __shared__ float fs[64 * D];
    int tid = threadIdx.x;
    #pragma unroll
    for (int i = 0; i < 16; ++i) {
        int idx = tid + i * 256;
        Wt[idx & 63][idx >> 6] = W_neigh[idx];
    }
    {
        long base4 = (long)blockIdx.x * 1024;
        const float4* f4 = (const float4*)feat;
        float4* s4 = (float4*)fs;
        #pragma unroll
        for (int i = 0; i < 4; ++i) {
            int idx = tid + i * 256;
            if (base4 + idx < (long)N_NODES * D / 4) s4[idx] = f4[base4 + idx];
        }
    }
    __syncthreads();

    int lane = tid & 63;
    int wave = tid >> 6;
    float w[D];
    #pragma unroll
    for (int k = 0; k < D; ++k) w[k] = Wt[k][lane];

    int r0 = blockIdx.x * 64 + wave * 16;
    #pragma unroll 1
    for (int rr = 0; rr < 16; ++rr) {
        int r = r0 + rr;
        if (r >= N_NODES) break;
        const float4* frow = (const float4*)(fs + (wave * 16 + rr) * D);
        float acc = 0.f;
        #pragma unroll
        for (int k4 = 0; k4 < 16; ++k4) {
            float4 f = frow[k4];
            acc += f.x * w[4*k4]   + f.y * w[4*k4+1]
                 + f.z * w[4*k4+2] + f.w * w[4*k4+3];
        }
        g[(size_t)r * D + lane] = __float2bfloat16(acc);
    }
}

// ---------------------------------------------------------------------------
// Aggregation: one wave per node, 4 EDGES PER ITERATION. Lane = 16*q + t:
// group q in [0,4) handles edge i+q, lane t in [0,16) covers features
// 4t..4t+3 via one uint2 (4 bf16) load -> one 128B coalesced row read per
// group. Wave-wide instruction stream amortized over 4 edges (~5 VALU/edge
// vs ~10 in the 1-edge-at-a-time version that measured 49% VALUBusy).
// Cross-group combine: shfl_xor 16/32 at the end. Zero atomics.
// ---------------------------------------------------------------------------
__global__ __launch_bounds__(256) void aggregate_kernel(
    const uint* __restrict__ g32, const unsigned* __restrict__ edata,
    const int* __restrict__ offsets, float* __restrict__ out)
{
    int v = blockIdx.x * 4 + (threadIdx.x >> 6);   // 25000*4 == N exactly
    int lane = threadIdx.x & 63;
    int q = lane >> 4;                 // edge group
    int t = lane & 15;                 // feature quad: features 4t..4t+3
    int lo = offsets[v], hi = offsets[v + 1];
    float4 acc = make_float4(0.f, 0.f, 0.f, 0.f);
    float sum = 0.f;

    for (int i = lo; i < hi; i += 4) {
        int e = i + q;
        int ec = (e < hi) ? e : hi - 1;            // in-bounds (loop => hi>lo)
        unsigned p = edata[ec];                    // 16B coalesced / 4 edges
        float w = (e < hi) ? __uint_as_float((p & 0x7FFFu) << 16) : 0.f;
        const uint2* grow = (const uint2*)(g32 + (size_t)(p >> 15) * (D / 2));
        uint2 u = grow[t];                         // 4 bf16 feats, 128B/row
        acc.x += w * __uint_as_float(u.x << 16);
        acc.y += w * __uint_as_float(u.x & 0xFFFF0000u);
        acc.z += w * __uint_as_float(u.y << 16);
        acc.w += w * __uint_as_float(u.y & 0xFFFF0000u);
        sum += w;
    }
    // combine the 4 groups (each lane t holds partials for feats 4t..4t+3)
    #pragma unroll
    for (int m = 16; m <= 32; m <<= 1) {
        acc.x += __shfl_xor(acc.x, m, 64);
        acc.y += __shfl_xor(acc.y, m, 64);
        acc.z += __shfl_xor(acc.z, m, 64);
        acc.w += __shfl_xor(acc.w, m, 64);
        sum   += __shfl_xor(sum,   m, 64);
    }
    if (hi > lo && q == 0) {                       // 16 lanes: float4 each
        float inv = 1.f / sum;
        float4* orow = (float4*)(out + (size_t)v * D);
        float4 c = orow[t];
        c.x += acc.x * inv; c.y += acc.y * inv;
        c.z += acc.z * inv; c.w += acc.w * inv;
        orow[t] = c;
    }
    // zero-degree nodes: reference gives h_neigh = 0 -> out keeps self part
}

// ---------------------------------------------------------------------------
extern "C" void kernel_launch(void* const* d_in, const int* in_sizes, int n_in,
                              void* d_out, int out_size, void* d_ws, size_t ws_size,
                              hipStream_t stream) {
    const float* feat    = (const float*)d_in[0];
    const float* rel     = (const float*)d_in[1];
    const float* W_self  = (const float*)d_in[2];
    const float* b_self  = (const float*)d_in[3];
    const float* W_neigh = (const float*)d_in[4];
    const float* b_neigh = (const float*)d_in[5];
    const float* attn_e  = (const float*)d_in[6];
    const int*   src     = (const int*)d_in[7];
    const int*   dst     = (const int*)d_in[8];
    float* out = (float*)d_out;

    // workspace layout (~33.3 MB)
    uint2* binned = (uint2*)d_ws;                               // 13.65 MB
    __hip_bfloat16* g = (__hip_bfloat16*)(binned + (size_t)NBUCK * BUCKET_CAP); // 12.8 MB
    unsigned* edata = (unsigned*)((char*)g + (size_t)N_NODES * D * 2);  // 6.4 MB
    int* offsets = (int*)(edata + N_EDGES);                     // [N+1]
    int* bucket_cursor = offsets + N_NODES + 1;                 // [NBUCK]

    hipMemsetAsync(bucket_cursor, 0, NBUCK * sizeof(int), stream);

    binning_kernel<<<(N_EDGES + P1_EPB - 1) / P1_EPB, 256, 0, stream>>>(
        (const float2*)rel, attn_e, src, dst, bucket_cursor, binned);
    csr_kernel<<<NBUCK, 1024, 0, stream>>>(
        bucket_cursor, binned, offsets, edata);
    gemm_self_kernel<<<(N_NODES + 63) / 64, 256, 0, stream>>>(
        feat, W_self, b_self, b_neigh, out);
    gemm_neigh_kernel<<<(N_NODES + 63) / 64, 256, 0, stream>>>(
        feat, W_neigh, g);
    aggregate_kernel<<<N_NODES / 4, 256, 0, stream>>>(
        (const uint*)g, edata, offsets, out);
}

// Round 8
// 217.622 us; speedup vs baseline: 2.9866x; 1.1986x over previous
//
#include <hip/hip_runtime.h>
#include <hip/hip_bf16.h>

#define N_NODES 100000
#define N_EDGES 1600000
#define D 64
#define NEG_SLOPE 0.2f

#define BSHIFT 10                                  // bucket = dst >> 10
#define BNODES 1024                                // nodes per bucket
#define NBUCK ((N_NODES + BNODES - 1) >> BSHIFT)   // 98
#define BUCKET_CAP 17408   // mean 16384, sigma ~127 -> 8-sigma headroom
#define P1_EPB 4096        // edges per binning block
#define P1_T 512
#define P1_IT (P1_EPB / P1_T)                      // 8 edges/thread

// ---------------------------------------------------------------------------
// Pass 1: bin edges by coarse dst bucket, LDS-staged so ALL global writes are
// coalesced runs (direct scatter wrote 100 MB of dirty partial lines for a
// 12.8 MB array -- write-line-granularity bound). Entry: {x = (src<<15)|wcode
// (bf16 weight, sign dropped), y = dst}. 512 threads: fewer serial
// iterations/thread, more waves to hide LDS-atomic latency.
// segment_max skipped: softmax is shift-invariant and |e| <= |a0|+|a1| is
// tiny, so exp() cannot overflow -- identical math to the reference.
// ---------------------------------------------------------------------------
__global__ __launch_bounds__(P1_T) void binning_kernel(
    const float2* __restrict__ rel, const float* __restrict__ attn_e,
    const int* __restrict__ src, const int* __restrict__ dst,
    int* __restrict__ bucket_cursor, uint2* __restrict__ binned)
{
    __shared__ uint2 staged1[P1_EPB];   // arrival order      (32 KB)
    __shared__ uint2 staged2[P1_EPB];   // bucket-sorted      (32 KB)
    __shared__ int cnt[NBUCK];
    __shared__ int excl[NBUCK];
    __shared__ int chunkbase[NBUCK];

    int tid = threadIdx.x;
    int e0 = blockIdx.x * P1_EPB;
    int n = min(P1_EPB, N_EDGES - e0);

    for (int b = tid; b < NBUCK; b += P1_T) cnt[b] = 0;
    __syncthreads();

    float a0 = attn_e[0], a1 = attn_e[1];

    int myslot[P1_IT];                  // fixed-index -> stays in VGPRs
    #pragma unroll
    for (int j = 0; j < P1_IT; ++j) {
        int i = tid + j * P1_T;
        if (i < n) {
            int e = e0 + i;
            float2 r = rel[e];
            float sc = r.x * a0 + r.y * a1;
            sc = (sc > 0.f) ? sc : NEG_SLOPE * sc;
            float ev = __expf(sc);
            unsigned u = __float_as_uint(ev) + 0x8000u;     // RNE to bf16
            unsigned wcode = (u >> 16) & 0x7FFFu;           // drop sign (ev>0)
            unsigned s = (unsigned)src[e];
            unsigned d = (unsigned)dst[e];
            staged1[i] = make_uint2((s << 15) | wcode, d);
            myslot[j] = atomicAdd(&cnt[d >> BSHIFT], 1);    // local ticket
        }
    }
    __syncthreads();
    if (tid == 0) {                     // 98-entry serial scan: trivial
        int run = 0;
        for (int b = 0; b < NBUCK; ++b) { excl[b] = run; run += cnt[b]; }
    }
    __syncthreads();
    #pragma unroll
    for (int j = 0; j < P1_IT; ++j) {   // LDS scatter into bucket order
        int i = tid + j * P1_T;
        if (i < n) {
            uint2 v = staged1[i];
            staged2[excl[v.y >> BSHIFT] + myslot[j]] = v;
        }
    }
    if (tid < NBUCK)                    // reserve contiguous global chunks
        chunkbase[tid] = atomicAdd(&bucket_cursor[tid], cnt[tid]);
    __syncthreads();
    for (int i = tid; i < n; i += P1_T) {  // coalesced runs per bucket chunk
        uint2 v = staged2[i];
        int b = (int)(v.y >> BSHIFT);
        binned[(size_t)b * BUCKET_CAP + chunkbase[b] + (i - excl[b])] = v;
    }
}

// ---------------------------------------------------------------------------
// Pass 2: one block per bucket, 1024 threads. LDS histogram -> LDS scan ->
// write offsets -> LDS scatter of packed values -> coalesced flush into the
// bucket's contiguous CSR range.
// ---------------------------------------------------------------------------
__global__ __launch_bounds__(1024) void csr_kernel(
    const int* __restrict__ bucket_cursor, const uint2* __restrict__ binned,
    int* __restrict__ offsets, unsigned* __restrict__ edata)
{
    __shared__ unsigned vals[BUCKET_CAP];   // 69.6 KB
    __shared__ int hist[BNODES];
    __shared__ int nexcl[BNODES];
    __shared__ int cur[BNODES];
    __shared__ int bc[NBUCK];
    __shared__ int base_sh;

    int b = blockIdx.x;
    int tid = threadIdx.x;

    if (tid < NBUCK) bc[tid] = bucket_cursor[tid];
    hist[tid] = 0;                      // 1024 threads cover BNODES exactly
    cur[tid] = 0;
    __syncthreads();
    if (tid == 0) {
        int s = 0;
        for (int i = 0; i < b; ++i) s += bc[i];
        base_sh = s;
    }
    __syncthreads();
    int count = bc[b];
    int base = base_sh;
    const uint2* bin = binned + (size_t)b * BUCKET_CAP;

    for (int i = tid; i < count; i += 1024)
        atomicAdd(&hist[bin[i].y & (BNODES - 1)], 1);
    __syncthreads();

    // inclusive Hillis-Steele over 1024 bins, one bin per thread
    int h = hist[tid];
    nexcl[tid] = h;
    __syncthreads();
    for (int d = 1; d < BNODES; d <<= 1) {
        int u = (tid >= d) ? nexcl[tid - d] : 0;
        __syncthreads();
        nexcl[tid] += u;
        __syncthreads();
    }
    int excl = nexcl[tid] - h;          // exclusive prefix
    __syncthreads();
    nexcl[tid] = excl;
    __syncthreads();

    int node = (b << BSHIFT) + tid;
    if (node < N_NODES) offsets[node] = base + excl;
    if (b == NBUCK - 1 && tid == 0) offsets[N_NODES] = N_EDGES;

    for (int i = tid; i < count; i += 1024) {     // LDS scatter
        uint2 e = bin[i];
        int d = e.y & (BNODES - 1);
        int t = atomicAdd(&cur[d], 1);
        vals[nexcl[d] + t] = e.x;
    }
    __syncthreads();
    for (int i = tid; i < count; i += 1024)       // coalesced flush
        edata[base + i] = vals[i];
}

// ---------------------------------------------------------------------------
// FUSED GEMM: 512 threads = 8 waves. Waves 0-3: out = feat@W_self^T + bias;
// waves 4-7: g = bf16(feat@W_neigh^T). One shared LDS feat staging (fused at
// the WAVE level, not thread level -- per-thread fusion of both weight sets
// hit the 256-VGPR cap and spilled 8x traffic in round 4; here each thread
// holds only ONE 64-reg weight column set, ~90 VGPRs).
// ---------------------------------------------------------------------------
__global__ __launch_bounds__(512) void gemm_fused_kernel(
    const float* __restrict__ feat, const float* __restrict__ W_self,
    const float* __restrict__ W_neigh, const float* __restrict__ b_self,
    const float* __restrict__ b_neigh, float* __restrict__ out,
    __hip_bfloat16* __restrict__ g)
{
    __shared__ float Wt[2][D][D + 1];          // 33.3 KB, transposed, padded
    __shared__ float fs[64 * D];               // 64 feat rows, 16 KB
    int tid = threadIdx.x;
    #pragma unroll
    for (int i = 0; i < 8; ++i) {
        int idx = tid + i * 512;               // coalesced global reads
        Wt[0][idx & 63][idx >> 6] = W_self[idx];
        Wt[1][idx & 63][idx >> 6] = W_neigh[idx];
    }
    {
        long base4 = (long)blockIdx.x * 1024;  // float4 index
        const float4* f4 = (const float4*)feat;
        float4* s4 = (float4*)fs;
        #pragma unroll
        for (int i = 0; i < 2; ++i) {
            int idx = tid + i * 512;
            if (base4 + idx < (long)N_NODES * D / 4) s4[idx] = f4[base4 + idx];
        }
    }
    __syncthreads();

    int lane = tid & 63;
    int wave = tid >> 6;
    int m = wave >> 2;                         // 0 = self, 1 = neigh
    int sw = wave & 3;                         // sub-wave within matrix
    float w[D];
    #pragma unroll
    for (int k = 0; k < D; ++k) w[k] = Wt[m][k][lane];   // conflict-free
    float bias = (m == 0) ? (b_self[lane] + b_neigh[lane]) : 0.f;

    int r0 = blockIdx.x * 64 + sw * 16;        // 16 rows per wave
    #pragma unroll 1
    for (int rr = 0; rr < 16; ++rr) {
        int r = r0 + rr;
        if (r >= N_NODES) break;
        const float4* frow = (const float4*)(fs + (sw * 16 + rr) * D);
        float acc = 0.f;
        #pragma unroll
        for (int k4 = 0; k4 < 16; ++k4) {
            float4 f = frow[k4];               // LDS broadcast (same addr)
            acc += f.x * w[4*k4]   + f.y * w[4*k4+1]
                 + f.z * w[4*k4+2] + f.w * w[4*k4+3];
        }
        if (m == 0) out[(size_t)r * D + lane] = acc + bias;
        else        g[(size_t)r * D + lane] = __float2bfloat16(acc);
    }
}

// ---------------------------------------------------------------------------
// Aggregation: one wave per node, 8 EDGES PER ITERATION (unroll x2 -> 2
// independent row gathers in flight per 16-lane group; round-7's single
// outstanding gather measured latency-bound: 34% VALU / 24% HBM / FETCH
// pinned at 94 MB). Lane = 16*q + t: group q handles edges i+q, i+4+q; lane
// t covers features 4t..4t+3 via uint2 (4 bf16). Zero atomics.
// ---------------------------------------------------------------------------
__global__ __launch_bounds__(256) void aggregate_kernel(
    const uint* __restrict__ g32, const unsigned* __restrict__ edata,
    const int* __restrict__ offsets, float* __restrict__ out)
{
    int v = blockIdx.x * 4 + (threadIdx.x >> 6);   // 25000*4 == N exactly
    int lane = threadIdx.x & 63;
    int q = lane >> 4;                 // edge group
    int t = lane & 15;                 // feature quad: features 4t..4t+3
    int lo = offsets[v], hi = offsets[v + 1];
    float4 acc = make_float4(0.f, 0.f, 0.f, 0.f);
    float sum = 0.f;

    for (int i = lo; i < hi; i += 8) {
        int e0 = i + q;
        int e1 = i + 4 + q;
        int ec0 = (e0 < hi) ? e0 : hi - 1;         // in-bounds (loop => hi>lo)
        int ec1 = (e1 < hi) ? e1 : hi - 1;
        unsigned p0 = edata[ec0];                  // coalesced, L2-hot
        unsigned p1 = edata[ec1];
        float w0 = (e0 < hi) ? __uint_as_float((p0 & 0x7FFFu) << 16) : 0.f;
        float w1 = (e1 < hi) ? __uint_as_float((p1 & 0x7FFFu) << 16) : 0.f;
        const uint2* r0 = (const uint2*)(g32 + (size_t)(p0 >> 15) * (D / 2));
        const uint2* r1 = (const uint2*)(g32 + (size_t)(p1 >> 15) * (D / 2));
        uint2 u0 = r0[t];                          // 2 gathers in flight
        uint2 u1 = r1[t];
        acc.x += w0 * __uint_as_float(u0.x << 16);
        acc.y += w0 * __uint_as_float(u0.x & 0xFFFF0000u);
        acc.z += w0 * __uint_as_float(u0.y << 16);
        acc.w += w0 * __uint_as_float(u0.y & 0xFFFF0000u);
        sum += w0;
        acc.x += w1 * __uint_as_float(u1.x << 16);
        acc.y += w1 * __uint_as_float(u1.x & 0xFFFF0000u);
        acc.z += w1 * __uint_as_float(u1.y << 16);
        acc.w += w1 * __uint_as_float(u1.y & 0xFFFF0000u);
        sum += w1;
    }
    // combine the 4 groups (each lane t holds partials for feats 4t..4t+3)
    #pragma unroll
    for (int mm = 16; mm <= 32; mm <<= 1) {
        acc.x += __shfl_xor(acc.x, mm, 64);
        acc.y += __shfl_xor(acc.y, mm, 64);
        acc.z += __shfl_xor(acc.z, mm, 64);
        acc.w += __shfl_xor(acc.w, mm, 64);
        sum   += __shfl_xor(sum,   mm, 64);
    }
    if (hi > lo && q == 0) {                       // 16 lanes: float4 each
        float inv = 1.f / sum;
        float4* orow = (float4*)(out + (size_t)v * D);
        float4 c = orow[t];
        c.x += acc.x * inv; c.y += acc.y * inv;
        c.z += acc.z * inv; c.w += acc.w * inv;
        orow[t] = c;
    }
    // zero-degree nodes: reference gives h_neigh = 0 -> out keeps self part
}

// ---------------------------------------------------------------------------
extern "C" void kernel_launch(void* const* d_in, const int* in_sizes, int n_in,
                              void* d_out, int out_size, void* d_ws, size_t ws_size,
                              hipStream_t stream) {
    const float* feat    = (const float*)d_in[0];
    const float* rel     = (const float*)d_in[1];
    const float* W_self  = (const float*)d_in[2];
    const float* b_self  = (const float*)d_in[3];
    const float* W_neigh = (const float*)d_in[4];
    const float* b_neigh = (const float*)d_in[5];
    const float* attn_e  = (const float*)d_in[6];
    const int*   src     = (const int*)d_in[7];
    const int*   dst     = (const int*)d_in[8];
    float* out = (float*)d_out;

    // workspace layout (~33.3 MB)
    uint2* binned = (uint2*)d_ws;                               // 13.65 MB
    __hip_bfloat16* g = (__hip_bfloat16*)(binned + (size_t)NBUCK * BUCKET_CAP); // 12.8 MB
    unsigned* edata = (unsigned*)((char*)g + (size_t)N_NODES * D * 2);  // 6.4 MB
    int* offsets = (int*)(edata + N_EDGES);                     // [N+1]
    int* bucket_cursor = offsets + N_NODES + 1;                 // [NBUCK]

    hipMemsetAsync(bucket_cursor, 0, NBUCK * sizeof(int), stream);

    binning_kernel<<<(N_EDGES + P1_EPB - 1) / P1_EPB, P1_T, 0, stream>>>(
        (const float2*)rel, attn_e, src, dst, bucket_cursor, binned);
    csr_kernel<<<NBUCK, 1024, 0, stream>>>(
        bucket_cursor, binned, offsets, edata);
    gemm_fused_kernel<<<(N_NODES + 63) / 64, 512, 0, stream>>>(
        feat, W_self, W_neigh, b_self, b_neigh, out, g);
    aggregate_kernel<<<N_NODES / 4, 256, 0, stream>>>(
        (const uint*)g, edata, offsets, out);
}